// Round 9
// baseline (133.902 us; speedup 1.0000x reference)
//
#include <hip/hip_runtime.h>
#include <hip/hip_bf16.h>
#include <hip/hip_fp16.h>

#define F 64            // feature dim (F_IN == HID == 64)
#define BSH 7           // nodes-per-bucket shift (128 nodes/bucket)
#define MAXB 512        // max buckets (supports N <= 65536 with uint16 csr)
#define CAPB 4096       // fixed per-bucket region (entries); true cnt ~2046 +/- 45
#define SLICE 12500     // edges per binscatter block (LDS sort buffer)

typedef short short8 __attribute__((ext_vector_type(8)));
typedef float f32x4  __attribute__((ext_vector_type(4)));
typedef unsigned short ushort_t;

__device__ __forceinline__ unsigned short f2bf(float x) {   // RNE float->bf16
    unsigned u = __float_as_uint(x);
    unsigned r = (u + 0x7fff + ((u >> 16) & 1)) >> 16;
    return (unsigned short)r;
}
__device__ __forceinline__ float bf2f(unsigned short h) {
    return __uint_as_float(((unsigned)h) << 16);
}

// ---------------- k_prep: W hi/lo fragments + bfill init + sentinel zero + pool zero ----
__global__ void k_prep(const float* __restrict__ W1, const float* __restrict__ W2,
                       short* __restrict__ Wh1, short* __restrict__ Wl1,
                       short* __restrict__ Wh2, short* __restrict__ Wl2,
                       int* __restrict__ bfill,
                       __half* __restrict__ xn, __half* __restrict__ hA,
                       __half* __restrict__ hB, int n,
                       float* __restrict__ pooled, int* __restrict__ cnt, int ng) {
    int b = blockIdx.x, t = threadIdx.x;
    if (b < 4) {                                 // W fragment prep (hi/lo bf16 split)
        const float* W = (b < 2) ? W1 : W2;
        short* WhF = (b < 2) ? Wh1 : Wh2;
        short* WlF = (b < 2) ? Wl1 : Wl2;
        int i = (b & 1) * 256 + t;               // 0..511 fragment-thread
        int lane = i & 63;
        int ct = i >> 6;
        int tt = ct & 1, c = ct >> 1;
        int j  = c * 16 + (lane & 15);
        int k0 = tt * 32 + (lane >> 4) * 8;
        #pragma unroll
        for (int e = 0; e < 8; ++e) {
            float xv = W[(k0 + e) * F + j];
            unsigned short hi = f2bf(xv);
            WhF[i * 8 + e] = (short)hi;
            WlF[i * 8 + e] = (short)f2bf(xv - bf2f(hi));
        }
    } else if (b == 4) {                         // bucket_fill init
        bfill[t]       = t * CAPB;
        bfill[t + 256] = (t + 256) * CAPB;
    } else if (b == 5) {                         // sentinel rows (row n) = zeros
        if (t < 32)      ((unsigned*)(xn + (size_t)n * F))[t]      = 0u;
        else if (t < 64) ((unsigned*)(hA + (size_t)n * F))[t - 32] = 0u;
        else if (t < 96) ((unsigned*)(hB + (size_t)n * F))[t - 64] = 0u;
    } else {                                     // zero pooled + cnt
        int idx = (b - 6) * 256 + t;
        if (idx < ng * F) pooled[idx] = 0.f;
        else if (idx < ng * F + ng) cnt[idx - ng * F] = 0;
    }
}

// ---------------- bin-scatter: LDS counting-sort slice, coalesced bucket-major writes ----
__global__ __launch_bounds__(512)
void k_binscatter(const int* __restrict__ src, const int* __restrict__ dst,
                  int e, int nbkt, int* __restrict__ bfill,
                  int* __restrict__ binned) {
    __shared__ int h[MAXB], pre[MAXB], base[MAXB], cur[MAXB];
    __shared__ int buf[SLICE];
    int t = threadIdx.x;
    int e0 = blockIdx.x * SLICE;
    int e1 = min(e0 + SLICE, e);
    int m = e1 - e0;
    if (m <= 0) return;
    for (int i = t; i < nbkt; i += 512) h[i] = 0;
    __syncthreads();
    for (int i = e0 + t; i < e1; i += 512) atomicAdd(&h[dst[i] >> BSH], 1);
    __syncthreads();
    {   // inclusive scan of h -> pre (512 threads cover MAXB)
        int v = (t < nbkt) ? h[t] : 0;
        pre[t] = v;
        __syncthreads();
        for (int off = 1; off < 512; off <<= 1) {
            int u = (t >= off) ? pre[t - off] : 0;
            __syncthreads();
            pre[t] += u;
            __syncthreads();
        }
    }
    for (int i = t; i < nbkt; i += 512) {        // reserve global chunks, init cursors
        int c = h[i];
        base[i] = c ? atomicAdd(&bfill[i], c) : 0;
        cur[i] = pre[i] - c;                     // exclusive prefix
    }
    __syncthreads();
    for (int i = e0 + t; i < e1; i += 512) {     // place into LDS, bucket-sorted
        int d = dst[i];
        int b = d >> BSH;
        int slot = atomicAdd(&cur[b], 1);
        buf[slot] = (src[i] << BSH) | (d & ((1 << BSH) - 1));
    }
    __syncthreads();
    for (int i = t; i < m; i += 512) {           // coalesced copy-out
        int lo = 0, hi = nbkt - 1;
        while (lo < hi) { int mid = (lo + hi) >> 1; if (pre[mid] <= i) lo = mid + 1; else hi = mid; }
        int off = i - (pre[lo] - h[lo]);
        binned[base[lo] + off] = buf[i];
    }
}

// ---------------- per-bucket CSR in LDS (rows padded to x16, sentinel row n, uint16 ids)
// + fused fp16 pre-scale of x -> xn for this bucket's nodes ----------------
__global__ void k_bincsr(const int* __restrict__ binned, const int* __restrict__ bfill,
                         const float* __restrict__ x, int n,
                         ushort_t* __restrict__ csr, int2* __restrict__ rowse,
                         float* __restrict__ dinv, __half* __restrict__ xn) {
    __shared__ int deg[1 << BSH], dp[1 << BSH], rp[1 << BSH], fill[1 << BSH];
    __shared__ int csr_l[CAPB];
    __shared__ int ovf;
    int b = blockIdx.x;
    int t = threadIdx.x;
    int n0 = b << BSH;
    int nn = min(n - n0, 1 << BSH);
    if (nn <= 0) return;
    int base = b * CAPB;
    int cnt = bfill[b] - base;                   // derived: no separate histogram pass
    if (t < (1 << BSH)) { deg[t] = 0; fill[t] = 0; }
    __syncthreads();
    for (int i = t; i < cnt; i += 256) atomicAdd(&deg[binned[base + i] & ((1 << BSH) - 1)], 1);
    __syncthreads();
    if (t < 128) { dp[t] = (deg[t] + 15) & ~15; rp[t] = dp[t]; }
    __syncthreads();
    for (int off = 1; off < 128; off <<= 1) {    // Hillis-Steele inclusive scan
        int u = 0;
        if (t < 128 && t >= off) u = rp[t - off];
        __syncthreads();
        if (t < 128) rp[t] += u;
        __syncthreads();
    }
    if (t == 0) ovf = (rp[127] > CAPB);
    __syncthreads();
    if (ovf) {                                   // ~impossible; unpadded fallback
        if (t < 128) { dp[t] = deg[t]; rp[t] = deg[t]; }
        __syncthreads();
        for (int off = 1; off < 128; off <<= 1) {
            int u = 0;
            if (t < 128 && t >= off) u = rp[t - off];
            __syncthreads();
            if (t < 128) rp[t] += u;
            __syncthreads();
        }
    }
    int total = rp[127];
    for (int i = t; i < total; i += 256) csr_l[i] = n;   // sentinel only where needed
    __syncthreads();
    for (int i = t; i < cnt; i += 256) {
        int pr = binned[base + i];
        int d = pr & ((1 << BSH) - 1);
        int pos = rp[d] - dp[d] + atomicAdd(&fill[d], 1);
        csr_l[pos] = pr >> BSH;
    }
    __syncthreads();
    for (int i = t; i < total; i += 256) csr[base + i] = (ushort_t)csr_l[i];  // coalesced
    if (t < nn) {
        int start = base + rp[t] - dp[t];
        rowse[n0 + t] = make_int2(start, start + dp[t]);
        dinv[n0 + t]  = rsqrtf((float)(deg[t] + 1));   // +1 self-loop
    }
    // fused pre-scale: xn[nd][j] = dinv[nd] * x[nd][j] (fp16, coalesced float2 reads)
    for (int i = t; i < nn * 32; i += 256) {
        int r = i >> 5, l = i & 31;
        float dv = rsqrtf((float)(deg[r] + 1));
        float2 v = ((const float2*)(x + (size_t)(n0 + r) * F))[l];
        ((__half2*)(xn + (size_t)(n0 + r) * F))[l] = __floats2half2_rn(v.x * dv, v.y * dv);
    }
}

// ---------------- fused layer: fp16 gather (uint16 csr, MLP=16, csr-prefetch) -> MFMA ---
// Block = 256 thr = 4 waves = 16 nodes. MODE 1: write dinv-scaled fp16 h.
// MODE 0 (last layer): skip h write; fuse mean-pool accumulation (batch sorted).
union SMem {
    struct { short Ah[16][72]; short Al[16][72]; };   // MFMA A-tiles (hi/lo)
    struct { float vals[16][68]; int bids[16]; };     // pool staging (layer 3)
};

template<int MODE>
__global__ __launch_bounds__(256, 8)
void k_layer(const __half* __restrict__ Hn, const int2* __restrict__ rowse,
             const ushort_t* __restrict__ csr, const float* __restrict__ dinv,
             const short* __restrict__ WhF, const short* __restrict__ WlF,
             const float* __restrict__ bias, __half* __restrict__ out,
             const int* __restrict__ batch, float* __restrict__ pooled,
             int* __restrict__ cnt, int n) {
    __shared__ SMem sm;
    __shared__ float sdinv[16];
    int t  = threadIdx.x;
    int w  = t >> 6, t6 = t & 63;
    int g  = t6 >> 5, l = t6 & 31;
    int nb0 = blockIdx.x * 16;
    const __half2* rows = (const __half2*)Hn;

    // ---- gather phase: 4 nodes per wave ----
    for (int q = 0; q < 4; ++q) {
        int ndl = w * 4 + q;
        int nd  = nb0 + ndl;
        float ax[8], ay[8];
        #pragma unroll
        for (int i = 0; i < 8; ++i) { ax[i] = 0.f; ay[i] = 0.f; }
        float dn = 0.f;
        if (nd < n) {
            dn = dinv[nd];
            if (g == 0) {                         // self row
                float2 f = __half22float2(rows[((size_t)nd << 5) + l]);
                ax[0] = f.x; ay[0] = f.y;
            }
            int2 se = rowse[nd];
            int e = se.x, e1 = se.y;
            int iters = ((e & 15) == 0) ? ((e1 - e) >> 4) : 0;
            if (iters > 0) {                      // padded (normal) path
                int4 cw = *(const int4*)(csr + e + 8 * g);
                for (int it = 0; it < iters; ++it) {
                    int4 nx = cw;                 // prefetch next csr word early
                    if (it + 1 < iters) nx = *(const int4*)(csr + e + 16 * (it + 1) + 8 * g);
                    int s[8] = { cw.x & 0xffff, (int)((unsigned)cw.x >> 16),
                                 cw.y & 0xffff, (int)((unsigned)cw.y >> 16),
                                 cw.z & 0xffff, (int)((unsigned)cw.z >> 16),
                                 cw.w & 0xffff, (int)((unsigned)cw.w >> 16) };
                    #pragma unroll
                    for (int i = 0; i < 8; ++i) {
                        float2 f = __half22float2(rows[((size_t)s[i] << 5) + l]);
                        ax[i] += f.x; ay[i] += f.y;
                    }
                    cw = nx;
                }
            }
            int er = e + 16 * iters;              // remainder (ovf fallback only)
            if (g == 0) {
                for (; er < e1; ++er) {
                    int s = csr[er];
                    float2 f = __half22float2(rows[((size_t)s << 5) + l]);
                    ax[7] += f.x; ay[7] += f.y;
                }
            }
        }
        float sx = ((ax[0] + ax[1]) + (ax[2] + ax[3])) + ((ax[4] + ax[5]) + (ax[6] + ax[7]));
        float sy = ((ay[0] + ay[1]) + (ay[2] + ay[3])) + ((ay[4] + ay[5]) + (ay[6] + ay[7]));
        sx += __shfl_xor(sx, 32);
        sy += __shfl_xor(sy, 32);
        sx *= dn; sy *= dn;
        if (g == 0) {
            unsigned short hx = f2bf(sx), hy = f2bf(sy);
            *(unsigned*)&sm.Ah[ndl][2 * l] = (unsigned)hx | ((unsigned)hy << 16);
            unsigned short lx = f2bf(sx - bf2f(hx)), ly = f2bf(sy - bf2f(hy));
            *(unsigned*)&sm.Al[ndl][2 * l] = (unsigned)lx | ((unsigned)ly << 16);
            if (l == 0) sdinv[ndl] = dn;
        }
    }
    __syncthreads();

    // ---- MFMA phase: wave w owns col-tile c=w ----
    int c  = w;
    int jj = t6 & 15;        // D col within tile / A row
    int kg = t6 >> 4;        // k-group
    const short8* WhP = (const short8*)WhF;
    const short8* WlP = (const short8*)WlF;
    short8 bh0 = WhP[(c * 2 + 0) * 64 + t6];
    short8 bh1 = WhP[(c * 2 + 1) * 64 + t6];
    short8 bl0 = WlP[(c * 2 + 0) * 64 + t6];
    short8 bl1 = WlP[(c * 2 + 1) * 64 + t6];
    short8 ah0 = *(const short8*)&sm.Ah[jj][kg * 8];
    short8 ah1 = *(const short8*)&sm.Ah[jj][32 + kg * 8];
    short8 al0 = *(const short8*)&sm.Al[jj][kg * 8];
    short8 al1 = *(const short8*)&sm.Al[jj][32 + kg * 8];

    float bv = bias[c * 16 + jj];
    f32x4 acc = {bv, bv, bv, bv};
    acc = __builtin_amdgcn_mfma_f32_16x16x32_bf16(ah0, bh0, acc, 0, 0, 0);
    acc = __builtin_amdgcn_mfma_f32_16x16x32_bf16(ah1, bh1, acc, 0, 0, 0);
    acc = __builtin_amdgcn_mfma_f32_16x16x32_bf16(al0, bh0, acc, 0, 0, 0);
    acc = __builtin_amdgcn_mfma_f32_16x16x32_bf16(al1, bh1, acc, 0, 0, 0);
    acc = __builtin_amdgcn_mfma_f32_16x16x32_bf16(ah0, bl0, acc, 0, 0, 0);
    acc = __builtin_amdgcn_mfma_f32_16x16x32_bf16(ah1, bl1, acc, 0, 0, 0);

    if (MODE == 1) {                 // write dinv-scaled fp16 h
        #pragma unroll
        for (int v = 0; v < 4; ++v) {
            int rr = kg * 4 + v;             // D row = local node
            int nd = nb0 + rr;
            if (nd < n) {
                float val = fmaxf(acc[v], 0.f) * sdinv[rr];
                out[(size_t)nd * F + c * 16 + jj] = __float2half(val);
            }
        }
    } else {                         // fused mean-pool accumulation (batch sorted)
        __syncthreads();             // done reading Ah/Al -> reuse LDS
        #pragma unroll
        for (int v = 0; v < 4; ++v) {
            int rr = kg * 4 + v;
            sm.vals[rr][c * 16 + jj] = fmaxf(acc[v], 0.f);
        }
        if (t < 16) sm.bids[t] = (nb0 + t < n) ? batch[nb0 + t] : -1;
        __syncthreads();
        if (t < 64) {                // per-column run-compressed atomics
            float accp = 0.f;
            int curg = sm.bids[0];
            for (int r = 0; r < 16; ++r) {
                int g2 = sm.bids[r];
                if (g2 < 0) break;
                if (g2 != curg) {
                    atomicAdd(&pooled[curg * F + t], accp);
                    curg = g2; accp = 0.f;
                }
                accp += sm.vals[r][t];
            }
            if (curg >= 0) atomicAdd(&pooled[curg * F + t], accp);
        } else if (t == 64) {        // node counts per graph
            int curg = sm.bids[0], cl = 0;
            for (int r = 0; r < 16; ++r) {
                int g2 = sm.bids[r];
                if (g2 < 0) break;
                if (g2 != curg) { atomicAdd(&cnt[curg], cl); curg = g2; cl = 0; }
                ++cl;
            }
            if (curg >= 0 && cl) atomicAdd(&cnt[curg], cl);
        }
    }
}

// ---------------- heads ----------------

__global__ void k_head(const float* __restrict__ pooled, const int* __restrict__ cnt,
                       const float* __restrict__ Wm, const float* __restrict__ bm,
                       const float* __restrict__ Wt, const float* __restrict__ bt,
                       float* __restrict__ out, int g) {
    int gid = (blockIdx.x * blockDim.x + threadIdx.x) >> 6;
    int j = threadIdx.x & 63;
    if (gid >= g) return;
    float c = fmaxf((float)cnt[gid], 1.f);
    float p = pooled[gid * F + j] / c;
    float m = p * Wm[j];
    float t = p * Wt[j];
    #pragma unroll
    for (int off = 32; off > 0; off >>= 1) {
        m += __shfl_down(m, off);
        t += __shfl_down(t, off);
    }
    if (j == 0) {
        out[gid]     = m + bm[0];
        out[g + gid] = t + bt[0];
    }
}

// ---------------- host driver ----------------

static inline size_t alignup(size_t x) { return (x + 255) & ~(size_t)255; }

extern "C" void kernel_launch(void* const* d_in, const int* in_sizes, int n_in,
                              void* d_out, int out_size, void* d_ws, size_t ws_size,
                              hipStream_t stream) {
    const float* x     = (const float*)d_in[0];
    const int*   eidx  = (const int*)d_in[1];
    const int*   batch = (const int*)d_in[2];
    const float* W1    = (const float*)d_in[3];
    const float* b1    = (const float*)d_in[4];
    const float* W2    = (const float*)d_in[5];
    const float* b2    = (const float*)d_in[6];
    const float* Wm    = (const float*)d_in[7];
    const float* bm    = (const float*)d_in[8];
    const float* Wt    = (const float*)d_in[9];
    const float* bt    = (const float*)d_in[10];
    float* out = (float*)d_out;

    const int N = in_sizes[0] / F;       // 50000
    const int E = in_sizes[1] / 2;       // 800000
    const int G = out_size / 2;          // 512
    const int* src = eidx;               // edge_index[0]
    const int* dst = eidx + E;           // edge_index[1]
    const int nbkt = (N + (1 << BSH) - 1) >> BSH;   // 391

    // workspace carve-up
    char* p = (char*)d_ws;
    float*    dinv   = (float*)p;    p += alignup(sizeof(float) * N);
    int2*     rowse  = (int2*)p;     p += alignup(sizeof(int2) * N);
    int*      bfill  = (int*)p;      p += alignup(sizeof(int) * MAXB);
    short*    Wh1    = (short*)p;    p += alignup(sizeof(short) * 4096);
    short*    Wl1    = (short*)p;    p += alignup(sizeof(short) * 4096);
    short*    Wh2    = (short*)p;    p += alignup(sizeof(short) * 4096);
    short*    Wl2    = (short*)p;    p += alignup(sizeof(short) * 4096);
    ushort_t* csr    = (ushort_t*)p; p += alignup(sizeof(ushort_t) * (size_t)nbkt * CAPB);
    int*      binned = (int*)p;      p += alignup(sizeof(int) * (size_t)nbkt * CAPB);
    __half*   xn     = (__half*)p;   p += alignup(sizeof(__half) * (size_t)(N + 1) * F);
    __half*   hA     = (__half*)p;   p += alignup(sizeof(__half) * (size_t)(N + 1) * F);
    __half*   hB     = (__half*)p;   p += alignup(sizeof(__half) * (size_t)(N + 1) * F);
    float*    pooled = (float*)p;    p += alignup(sizeof(float) * G * F);
    int*      cnt    = (int*)p;      p += alignup(sizeof(int) * G);

    const int TB = 256;

    // ---- prep: W fragments, bfill init, sentinel zeros, pool zeros ----
    int gPrep = 6 + (G * F + G + TB - 1) / TB;
    k_prep<<<gPrep, TB, 0, stream>>>(W1, W2, Wh1, Wl1, Wh2, Wl2, bfill,
                                     xn, hA, hB, N, pooled, cnt, G);

    // ---- CSR build: LDS-sorted bin-scatter + per-bucket CSR, fused scale ----
    int gS = (E + SLICE - 1) / SLICE;    // 64 blocks
    k_binscatter<<<gS, 512, 0, stream>>>(src, dst, E, nbkt, bfill, binned);
    k_bincsr    <<<nbkt, TB, 0, stream>>>(binned, bfill, x, N, csr, rowse, dinv, xn);

    // ---- fused layers: 16 nodes per block, fp16 gather + MFMA; layer 3 fuses pooling ----
    int gT = (N + 15) / 16;              // 3125 blocks
    k_layer<1><<<gT, TB, 0, stream>>>(xn, rowse, csr, dinv, Wh1, Wl1, b1, hA,
                                      batch, pooled, cnt, N);
    k_layer<1><<<gT, TB, 0, stream>>>(hA, rowse, csr, dinv, Wh2, Wl2, b2, hB,
                                      batch, pooled, cnt, N);
    k_layer<0><<<gT, TB, 0, stream>>>(hB, rowse, csr, dinv, Wh2, Wl2, b2, hA,
                                      batch, pooled, cnt, N);

    // ---- heads ----
    int gH = (G * F + TB - 1) / TB;
    k_head<<<gH, TB, 0, stream>>>(pooled, cnt, Wm, bm, Wt, bt, out, G);
}

// Round 10
// 121.266 us; speedup vs baseline: 1.1042x; 1.1042x over previous
//
#include <hip/hip_runtime.h>
#include <hip/hip_bf16.h>
#include <hip/hip_fp16.h>

#define F 64            // feature dim (F_IN == HID == 64)
#define BSH 7           // nodes-per-bucket shift (128 nodes/bucket)
#define MAXB 512        // max buckets (supports N <= 65536 with uint16 csr)
#define CAPB 4096       // fixed per-bucket region (entries); true cnt ~2046 +/- 45

typedef short short8 __attribute__((ext_vector_type(8)));
typedef float f32x4  __attribute__((ext_vector_type(4)));
typedef unsigned short ushort_t;

__device__ __forceinline__ unsigned short f2bf(float x) {   // RNE float->bf16
    unsigned u = __float_as_uint(x);
    unsigned r = (u + 0x7fff + ((u >> 16) & 1)) >> 16;
    return (unsigned short)r;
}
__device__ __forceinline__ float bf2f(unsigned short h) {
    return __uint_as_float(((unsigned)h) << 16);
}

// ---------------- k_prep: W hi/lo fragments + bfill init + sentinel zero + pool zero ----
__global__ void k_prep(const float* __restrict__ W1, const float* __restrict__ W2,
                       short* __restrict__ Wh1, short* __restrict__ Wl1,
                       short* __restrict__ Wh2, short* __restrict__ Wl2,
                       int* __restrict__ bfill,
                       __half* __restrict__ xn, __half* __restrict__ hA,
                       __half* __restrict__ hB, int n,
                       float* __restrict__ pooled, int* __restrict__ cnt, int ng) {
    int b = blockIdx.x, t = threadIdx.x;
    if (b < 4) {                                 // W fragment prep (hi/lo bf16 split)
        const float* W = (b < 2) ? W1 : W2;
        short* WhF = (b < 2) ? Wh1 : Wh2;
        short* WlF = (b < 2) ? Wl1 : Wl2;
        int i = (b & 1) * 256 + t;               // 0..511 fragment-thread
        int lane = i & 63;
        int ct = i >> 6;
        int tt = ct & 1, c = ct >> 1;
        int j  = c * 16 + (lane & 15);
        int k0 = tt * 32 + (lane >> 4) * 8;
        #pragma unroll
        for (int e = 0; e < 8; ++e) {
            float xv = W[(k0 + e) * F + j];
            unsigned short hi = f2bf(xv);
            WhF[i * 8 + e] = (short)hi;
            WlF[i * 8 + e] = (short)f2bf(xv - bf2f(hi));
        }
    } else if (b == 4) {                         // bucket_fill init
        bfill[t]       = t * CAPB;
        bfill[t + 256] = (t + 256) * CAPB;
    } else if (b == 5) {                         // sentinel rows (row n) = zeros
        if (t < 32)      ((unsigned*)(xn + (size_t)n * F))[t]      = 0u;
        else if (t < 64) ((unsigned*)(hA + (size_t)n * F))[t - 32] = 0u;
        else if (t < 96) ((unsigned*)(hB + (size_t)n * F))[t - 64] = 0u;
    } else {                                     // zero pooled + cnt
        int idx = (b - 6) * 256 + t;
        if (idx < ng * F) pooled[idx] = 0.f;
        else if (idx < ng * F + ng) cnt[idx - ng * F] = 0;
    }
}

// ---------------- bin-scatter: reserve per-bucket chunks, write packed (src<<7|ldst) ----
// (round-8 version: 128 blocks x 256 thr, LDS histogram + direct global chunk scatter)
__global__ void k_binscatter(const int* __restrict__ src, const int* __restrict__ dst,
                             int e, int nbkt, int* __restrict__ bucket_fill,
                             int* __restrict__ binned) {
    __shared__ int h[MAXB], base[MAXB];
    int t = threadIdx.x;
    int perblk = (e + gridDim.x - 1) / gridDim.x;
    int e0 = blockIdx.x * perblk;
    int e1 = min(e0 + perblk, e);
    for (int i = t; i < nbkt; i += 256) h[i] = 0;
    __syncthreads();
    for (int i = e0 + t; i < e1; i += 256) atomicAdd(&h[dst[i] >> BSH], 1);
    __syncthreads();
    for (int i = t; i < nbkt; i += 256) {
        int c = h[i];
        base[i] = c ? atomicAdd(&bucket_fill[i], c) : 0;
        h[i] = 0;                               // reuse as cursor
    }
    __syncthreads();
    for (int i = e0 + t; i < e1; i += 256) {
        int d = dst[i];
        int b = d >> BSH;
        int r = atomicAdd(&h[b], 1);
        binned[base[b] + r] = (src[i] << BSH) | (d & ((1 << BSH) - 1));
    }
}

// ---------------- per-bucket CSR in LDS (rows padded to x16, sentinel row n, uint16 ids)
// + fused fp16 pre-scale of x -> xn for this bucket's nodes ----------------
__global__ void k_bincsr(const int* __restrict__ binned, const int* __restrict__ bfill,
                         const float* __restrict__ x, int n,
                         ushort_t* __restrict__ csr, int2* __restrict__ rowse,
                         float* __restrict__ dinv, __half* __restrict__ xn) {
    __shared__ int deg[1 << BSH], dp[1 << BSH], rp[1 << BSH], fill[1 << BSH];
    __shared__ int csr_l[CAPB];
    __shared__ int ovf;
    int b = blockIdx.x;
    int t = threadIdx.x;
    int n0 = b << BSH;
    int nn = min(n - n0, 1 << BSH);
    if (nn <= 0) return;
    int base = b * CAPB;
    int cnt = bfill[b] - base;                   // derived: no separate histogram pass
    if (t < (1 << BSH)) { deg[t] = 0; fill[t] = 0; }
    __syncthreads();
    for (int i = t; i < cnt; i += 256) atomicAdd(&deg[binned[base + i] & ((1 << BSH) - 1)], 1);
    __syncthreads();
    if (t < 128) { dp[t] = (deg[t] + 15) & ~15; rp[t] = dp[t]; }
    __syncthreads();
    for (int off = 1; off < 128; off <<= 1) {    // Hillis-Steele inclusive scan
        int u = 0;
        if (t < 128 && t >= off) u = rp[t - off];
        __syncthreads();
        if (t < 128) rp[t] += u;
        __syncthreads();
    }
    if (t == 0) ovf = (rp[127] > CAPB);
    __syncthreads();
    if (ovf) {                                   // ~impossible; unpadded fallback
        if (t < 128) { dp[t] = deg[t]; rp[t] = deg[t]; }
        __syncthreads();
        for (int off = 1; off < 128; off <<= 1) {
            int u = 0;
            if (t < 128 && t >= off) u = rp[t - off];
            __syncthreads();
            if (t < 128) rp[t] += u;
            __syncthreads();
        }
    }
    int total = rp[127];
    for (int i = t; i < total; i += 256) csr_l[i] = n;   // sentinel only where needed
    __syncthreads();
    for (int i = t; i < cnt; i += 256) {
        int pr = binned[base + i];
        int d = pr & ((1 << BSH) - 1);
        int pos = rp[d] - dp[d] + atomicAdd(&fill[d], 1);
        csr_l[pos] = pr >> BSH;
    }
    __syncthreads();
    for (int i = t; i < total; i += 256) csr[base + i] = (ushort_t)csr_l[i];  // coalesced
    if (t < nn) {
        int start = base + rp[t] - dp[t];
        rowse[n0 + t] = make_int2(start, start + dp[t]);
        dinv[n0 + t]  = rsqrtf((float)(deg[t] + 1));   // +1 self-loop
    }
    // fused pre-scale: xn[nd][j] = dinv[nd] * x[nd][j] (fp16, coalesced float2 reads)
    for (int i = t; i < nn * 32; i += 256) {
        int r = i >> 5, l = i & 31;
        float dv = rsqrtf((float)(deg[r] + 1));
        float2 v = ((const float2*)(x + (size_t)(n0 + r) * F))[l];
        ((__half2*)(xn + (size_t)(n0 + r) * F))[l] = __floats2half2_rn(v.x * dv, v.y * dv);
    }
}

// ---------------- fused layer: fp16 gather (uint16 csr, MLP=16, csr-prefetch) -> MFMA ---
// Block = 256 thr = 4 waves = 16 nodes. MODE 1: write dinv-scaled fp16 h.
// MODE 0 (last layer): skip h write; fuse mean-pool accumulation (batch sorted).
union SMem {
    struct { short Ah[16][72]; short Al[16][72]; };   // MFMA A-tiles (hi/lo)
    struct { float vals[16][68]; int bids[16]; };     // pool staging (layer 3)
};

template<int MODE>
__global__ __launch_bounds__(256, 8)
void k_layer(const __half* __restrict__ Hn, const int2* __restrict__ rowse,
             const ushort_t* __restrict__ csr, const float* __restrict__ dinv,
             const short* __restrict__ WhF, const short* __restrict__ WlF,
             const float* __restrict__ bias, __half* __restrict__ out,
             const int* __restrict__ batch, float* __restrict__ pooled,
             int* __restrict__ cnt, int n) {
    __shared__ SMem sm;
    __shared__ float sdinv[16];
    int t  = threadIdx.x;
    int w  = t >> 6, t6 = t & 63;
    int g  = t6 >> 5, l = t6 & 31;
    int nb0 = blockIdx.x * 16;
    const __half2* rows = (const __half2*)Hn;

    // ---- gather phase: 4 nodes per wave ----
    for (int q = 0; q < 4; ++q) {
        int ndl = w * 4 + q;
        int nd  = nb0 + ndl;
        float ax[8], ay[8];
        #pragma unroll
        for (int i = 0; i < 8; ++i) { ax[i] = 0.f; ay[i] = 0.f; }
        float dn = 0.f;
        if (nd < n) {
            dn = dinv[nd];
            if (g == 0) {                         // self row
                float2 f = __half22float2(rows[((size_t)nd << 5) + l]);
                ax[0] = f.x; ay[0] = f.y;
            }
            int2 se = rowse[nd];
            int e = se.x, e1 = se.y;
            int iters = ((e & 15) == 0) ? ((e1 - e) >> 4) : 0;
            if (iters > 0) {                      // padded (normal) path
                int4 cw = *(const int4*)(csr + e + 8 * g);
                for (int it = 0; it < iters; ++it) {
                    int4 nx = cw;                 // prefetch next csr word early
                    if (it + 1 < iters) nx = *(const int4*)(csr + e + 16 * (it + 1) + 8 * g);
                    int s[8] = { cw.x & 0xffff, (int)((unsigned)cw.x >> 16),
                                 cw.y & 0xffff, (int)((unsigned)cw.y >> 16),
                                 cw.z & 0xffff, (int)((unsigned)cw.z >> 16),
                                 cw.w & 0xffff, (int)((unsigned)cw.w >> 16) };
                    #pragma unroll
                    for (int i = 0; i < 8; ++i) {
                        float2 f = __half22float2(rows[((size_t)s[i] << 5) + l]);
                        ax[i] += f.x; ay[i] += f.y;
                    }
                    cw = nx;
                }
            }
            int er = e + 16 * iters;              // remainder (ovf fallback only)
            if (g == 0) {
                for (; er < e1; ++er) {
                    int s = csr[er];
                    float2 f = __half22float2(rows[((size_t)s << 5) + l]);
                    ax[7] += f.x; ay[7] += f.y;
                }
            }
        }
        float sx = ((ax[0] + ax[1]) + (ax[2] + ax[3])) + ((ax[4] + ax[5]) + (ax[6] + ax[7]));
        float sy = ((ay[0] + ay[1]) + (ay[2] + ay[3])) + ((ay[4] + ay[5]) + (ay[6] + ay[7]));
        sx += __shfl_xor(sx, 32);
        sy += __shfl_xor(sy, 32);
        sx *= dn; sy *= dn;
        if (g == 0) {
            unsigned short hx = f2bf(sx), hy = f2bf(sy);
            *(unsigned*)&sm.Ah[ndl][2 * l] = (unsigned)hx | ((unsigned)hy << 16);
            unsigned short lx = f2bf(sx - bf2f(hx)), ly = f2bf(sy - bf2f(hy));
            *(unsigned*)&sm.Al[ndl][2 * l] = (unsigned)lx | ((unsigned)ly << 16);
            if (l == 0) sdinv[ndl] = dn;
        }
    }
    __syncthreads();

    // ---- MFMA phase: wave w owns col-tile c=w ----
    int c  = w;
    int jj = t6 & 15;        // D col within tile / A row
    int kg = t6 >> 4;        // k-group
    const short8* WhP = (const short8*)WhF;
    const short8* WlP = (const short8*)WlF;
    short8 bh0 = WhP[(c * 2 + 0) * 64 + t6];
    short8 bh1 = WhP[(c * 2 + 1) * 64 + t6];
    short8 bl0 = WlP[(c * 2 + 0) * 64 + t6];
    short8 bl1 = WlP[(c * 2 + 1) * 64 + t6];
    short8 ah0 = *(const short8*)&sm.Ah[jj][kg * 8];
    short8 ah1 = *(const short8*)&sm.Ah[jj][32 + kg * 8];
    short8 al0 = *(const short8*)&sm.Al[jj][kg * 8];
    short8 al1 = *(const short8*)&sm.Al[jj][32 + kg * 8];

    float bv = bias[c * 16 + jj];
    f32x4 acc = {bv, bv, bv, bv};
    acc = __builtin_amdgcn_mfma_f32_16x16x32_bf16(ah0, bh0, acc, 0, 0, 0);
    acc = __builtin_amdgcn_mfma_f32_16x16x32_bf16(ah1, bh1, acc, 0, 0, 0);
    acc = __builtin_amdgcn_mfma_f32_16x16x32_bf16(al0, bh0, acc, 0, 0, 0);
    acc = __builtin_amdgcn_mfma_f32_16x16x32_bf16(al1, bh1, acc, 0, 0, 0);
    acc = __builtin_amdgcn_mfma_f32_16x16x32_bf16(ah0, bl0, acc, 0, 0, 0);
    acc = __builtin_amdgcn_mfma_f32_16x16x32_bf16(ah1, bl1, acc, 0, 0, 0);

    if (MODE == 1) {                 // write dinv-scaled fp16 h
        #pragma unroll
        for (int v = 0; v < 4; ++v) {
            int rr = kg * 4 + v;             // D row = local node
            int nd = nb0 + rr;
            if (nd < n) {
                float val = fmaxf(acc[v], 0.f) * sdinv[rr];
                out[(size_t)nd * F + c * 16 + jj] = __float2half(val);
            }
        }
    } else {                         // fused mean-pool accumulation (batch sorted)
        __syncthreads();             // done reading Ah/Al -> reuse LDS
        #pragma unroll
        for (int v = 0; v < 4; ++v) {
            int rr = kg * 4 + v;
            sm.vals[rr][c * 16 + jj] = fmaxf(acc[v], 0.f);
        }
        if (t < 16) sm.bids[t] = (nb0 + t < n) ? batch[nb0 + t] : -1;
        __syncthreads();
        if (t < 64) {                // per-column run-compressed atomics
            float accp = 0.f;
            int curg = sm.bids[0];
            for (int r = 0; r < 16; ++r) {
                int g2 = sm.bids[r];
                if (g2 < 0) break;
                if (g2 != curg) {
                    atomicAdd(&pooled[curg * F + t], accp);
                    curg = g2; accp = 0.f;
                }
                accp += sm.vals[r][t];
            }
            if (curg >= 0) atomicAdd(&pooled[curg * F + t], accp);
        } else if (t == 64) {        // node counts per graph
            int curg = sm.bids[0], cl = 0;
            for (int r = 0; r < 16; ++r) {
                int g2 = sm.bids[r];
                if (g2 < 0) break;
                if (g2 != curg) { atomicAdd(&cnt[curg], cl); curg = g2; cl = 0; }
                ++cl;
            }
            if (curg >= 0 && cl) atomicAdd(&cnt[curg], cl);
        }
    }
}

// ---------------- heads ----------------

__global__ void k_head(const float* __restrict__ pooled, const int* __restrict__ cnt,
                       const float* __restrict__ Wm, const float* __restrict__ bm,
                       const float* __restrict__ Wt, const float* __restrict__ bt,
                       float* __restrict__ out, int g) {
    int gid = (blockIdx.x * blockDim.x + threadIdx.x) >> 6;
    int j = threadIdx.x & 63;
    if (gid >= g) return;
    float c = fmaxf((float)cnt[gid], 1.f);
    float p = pooled[gid * F + j] / c;
    float m = p * Wm[j];
    float t = p * Wt[j];
    #pragma unroll
    for (int off = 32; off > 0; off >>= 1) {
        m += __shfl_down(m, off);
        t += __shfl_down(t, off);
    }
    if (j == 0) {
        out[gid]     = m + bm[0];
        out[g + gid] = t + bt[0];
    }
}

// ---------------- host driver ----------------

static inline size_t alignup(size_t x) { return (x + 255) & ~(size_t)255; }

extern "C" void kernel_launch(void* const* d_in, const int* in_sizes, int n_in,
                              void* d_out, int out_size, void* d_ws, size_t ws_size,
                              hipStream_t stream) {
    const float* x     = (const float*)d_in[0];
    const int*   eidx  = (const int*)d_in[1];
    const int*   batch = (const int*)d_in[2];
    const float* W1    = (const float*)d_in[3];
    const float* b1    = (const float*)d_in[4];
    const float* W2    = (const float*)d_in[5];
    const float* b2    = (const float*)d_in[6];
    const float* Wm    = (const float*)d_in[7];
    const float* bm    = (const float*)d_in[8];
    const float* Wt    = (const float*)d_in[9];
    const float* bt    = (const float*)d_in[10];
    float* out = (float*)d_out;

    const int N = in_sizes[0] / F;       // 50000
    const int E = in_sizes[1] / 2;       // 800000
    const int G = out_size / 2;          // 512
    const int* src = eidx;               // edge_index[0]
    const int* dst = eidx + E;           // edge_index[1]
    const int nbkt = (N + (1 << BSH) - 1) >> BSH;   // 391

    // workspace carve-up
    char* p = (char*)d_ws;
    float*    dinv   = (float*)p;    p += alignup(sizeof(float) * N);
    int2*     rowse  = (int2*)p;     p += alignup(sizeof(int2) * N);
    int*      bfill  = (int*)p;      p += alignup(sizeof(int) * MAXB);
    short*    Wh1    = (short*)p;    p += alignup(sizeof(short) * 4096);
    short*    Wl1    = (short*)p;    p += alignup(sizeof(short) * 4096);
    short*    Wh2    = (short*)p;    p += alignup(sizeof(short) * 4096);
    short*    Wl2    = (short*)p;    p += alignup(sizeof(short) * 4096);
    ushort_t* csr    = (ushort_t*)p; p += alignup(sizeof(ushort_t) * (size_t)nbkt * CAPB);
    int*      binned = (int*)p;      p += alignup(sizeof(int) * (size_t)nbkt * CAPB);
    __half*   xn     = (__half*)p;   p += alignup(sizeof(__half) * (size_t)(N + 1) * F);
    __half*   hA     = (__half*)p;   p += alignup(sizeof(__half) * (size_t)(N + 1) * F);
    __half*   hB     = (__half*)p;   p += alignup(sizeof(__half) * (size_t)(N + 1) * F);
    float*    pooled = (float*)p;    p += alignup(sizeof(float) * G * F);
    int*      cnt    = (int*)p;      p += alignup(sizeof(int) * G);

    const int TB = 256;

    // ---- prep: W fragments, bfill init, sentinel zeros, pool zeros ----
    int gPrep = 6 + (G * F + G + TB - 1) / TB;
    k_prep<<<gPrep, TB, 0, stream>>>(W1, W2, Wh1, Wl1, Wh2, Wl2, bfill,
                                     xn, hA, hB, N, pooled, cnt, G);

    // ---- CSR build: bucketed counting sort (2 passes), padded rows, fused scale ----
    k_binscatter<<<128, TB, 0, stream>>>(src, dst, E, nbkt, bfill, binned);
    k_bincsr    <<<nbkt, TB, 0, stream>>>(binned, bfill, x, N, csr, rowse, dinv, xn);

    // ---- fused layers: 16 nodes per block, fp16 gather + MFMA; layer 3 fuses pooling ----
    int gT = (N + 15) / 16;              // 3125 blocks
    k_layer<1><<<gT, TB, 0, stream>>>(xn, rowse, csr, dinv, Wh1, Wl1, b1, hA,
                                      batch, pooled, cnt, N);
    k_layer<1><<<gT, TB, 0, stream>>>(hA, rowse, csr, dinv, Wh2, Wl2, b2, hB,
                                      batch, pooled, cnt, N);
    k_layer<0><<<gT, TB, 0, stream>>>(hB, rowse, csr, dinv, Wh2, Wl2, b2, hA,
                                      batch, pooled, cnt, N);

    // ---- heads ----
    int gH = (G * F + TB - 1) / TB;
    k_head<<<gH, TB, 0, stream>>>(pooled, cnt, Wm, bm, Wt, bt, out, G);
}

// Round 11
// 120.177 us; speedup vs baseline: 1.1142x; 1.0091x over previous
//
#include <hip/hip_runtime.h>
#include <hip/hip_bf16.h>
#include <hip/hip_fp16.h>

#define F 64            // feature dim (F_IN == HID == 64)
#define BSH 7           // nodes-per-bucket shift (128 nodes/bucket)
#define MAXB 512        // max buckets (supports N <= 65536 with uint16 csr)
#define CAPB 4096       // fixed per-bucket region (entries); true cnt ~2046 +/- 45
#define PREPB 8         // extra prep blocks appended to k_bincsr grid

typedef short short8 __attribute__((ext_vector_type(8)));
typedef float f32x4  __attribute__((ext_vector_type(4)));
typedef unsigned short ushort_t;

__device__ __forceinline__ unsigned short f2bf(float x) {   // RNE float->bf16
    unsigned u = __float_as_uint(x);
    unsigned r = (u + 0x7fff + ((u >> 16) & 1)) >> 16;
    return (unsigned short)r;
}
__device__ __forceinline__ float bf2f(unsigned short h) {
    return __uint_as_float(((unsigned)h) << 16);
}

// ---------------- k_prep0: bucket_fill init only (must precede binscatter) ----------------
__global__ void k_prep0(int* __restrict__ bfill) {
    int t = threadIdx.x;                 // 512 threads
    if (t < MAXB) bfill[t] = t * CAPB;
}

// ---------------- bin-scatter: reserve per-bucket chunks, write packed (src<<7|ldst) ----
__global__ void k_binscatter(const int* __restrict__ src, const int* __restrict__ dst,
                             int e, int nbkt, int* __restrict__ bucket_fill,
                             int* __restrict__ binned) {
    __shared__ int h[MAXB], base[MAXB];
    int t = threadIdx.x;
    int perblk = (e + gridDim.x - 1) / gridDim.x;
    int e0 = blockIdx.x * perblk;
    int e1 = min(e0 + perblk, e);
    for (int i = t; i < nbkt; i += 256) h[i] = 0;
    __syncthreads();
    for (int i = e0 + t; i < e1; i += 256) atomicAdd(&h[dst[i] >> BSH], 1);
    __syncthreads();
    for (int i = t; i < nbkt; i += 256) {
        int c = h[i];
        base[i] = c ? atomicAdd(&bucket_fill[i], c) : 0;
        h[i] = 0;                               // reuse as cursor
    }
    __syncthreads();
    for (int i = e0 + t; i < e1; i += 256) {
        int d = dst[i];
        int b = d >> BSH;
        int r = atomicAdd(&h[b], 1);
        binned[base[b] + r] = (src[i] << BSH) | (d & ((1 << BSH) - 1));
    }
}

// ---------------- per-bucket CSR in LDS (rows padded to x16, sentinel row n, uint16 ids)
// + fused fp16 pre-scale of x -> xn  + (extra blocks) W-frag/sentinel/pool prep ----------
__global__ void k_bincsr(const int* __restrict__ binned, const int* __restrict__ bfill,
                         const float* __restrict__ x, int n, int nbkt,
                         ushort_t* __restrict__ csr, int2* __restrict__ rowse,
                         float* __restrict__ dinv, __half* __restrict__ xn,
                         const float* __restrict__ W1, const float* __restrict__ W2,
                         short* __restrict__ Wh1, short* __restrict__ Wl1,
                         short* __restrict__ Wh2, short* __restrict__ Wl2,
                         __half* __restrict__ hA, __half* __restrict__ hB,
                         float* __restrict__ pooled, int* __restrict__ cnt2, int ng) {
    int b = blockIdx.x;
    int t = threadIdx.x;
    if (b >= nbkt) {                             // ---- prep-extra blocks ----
        int bp = b - nbkt;
        if (bp < 4) {                            // W fragment prep (hi/lo bf16 split)
            const float* W = (bp < 2) ? W1 : W2;
            short* WhF = (bp < 2) ? Wh1 : Wh2;
            short* WlF = (bp < 2) ? Wl1 : Wl2;
            int i = (bp & 1) * 256 + t;          // 0..511 fragment-thread
            int lane = i & 63;
            int ct = i >> 6;
            int tt = ct & 1, c = ct >> 1;
            int j  = c * 16 + (lane & 15);
            int k0 = tt * 32 + (lane >> 4) * 8;
            #pragma unroll
            for (int e = 0; e < 8; ++e) {
                float xv = W[(k0 + e) * F + j];
                unsigned short hi = f2bf(xv);
                WhF[i * 8 + e] = (short)hi;
                WlF[i * 8 + e] = (short)f2bf(xv - bf2f(hi));
            }
        } else if (bp == 4) {                    // sentinel rows (row n) = zeros
            if (t < 32)      ((unsigned*)(xn + (size_t)n * F))[t]      = 0u;
            else if (t < 64) ((unsigned*)(hA + (size_t)n * F))[t - 32] = 0u;
            else if (t < 96) ((unsigned*)(hB + (size_t)n * F))[t - 64] = 0u;
        } else {                                 // zero pooled + cnt (3 blocks strided)
            int tot = ng * F + ng;
            for (int i = (bp - 5) * 256 + t; i < tot; i += 3 * 256) {
                if (i < ng * F) pooled[i] = 0.f;
                else cnt2[i - ng * F] = 0;
            }
        }
        return;
    }
    __shared__ int deg[1 << BSH], dp[1 << BSH], rp[1 << BSH], fill[1 << BSH];
    __shared__ int csr_l[CAPB];
    __shared__ int ovf;
    int n0 = b << BSH;
    int nn = min(n - n0, 1 << BSH);
    if (nn <= 0) return;
    int base = b * CAPB;
    int cnt = bfill[b] - base;                   // derived: no separate histogram pass
    if (t < (1 << BSH)) { deg[t] = 0; fill[t] = 0; }
    __syncthreads();
    for (int i = t; i < cnt; i += 256) atomicAdd(&deg[binned[base + i] & ((1 << BSH) - 1)], 1);
    __syncthreads();
    if (t < 128) { dp[t] = (deg[t] + 15) & ~15; rp[t] = dp[t]; }
    __syncthreads();
    for (int off = 1; off < 128; off <<= 1) {    // Hillis-Steele inclusive scan
        int u = 0;
        if (t < 128 && t >= off) u = rp[t - off];
        __syncthreads();
        if (t < 128) rp[t] += u;
        __syncthreads();
    }
    if (t == 0) ovf = (rp[127] > CAPB);
    __syncthreads();
    if (ovf) {                                   // ~impossible; unpadded fallback
        if (t < 128) { dp[t] = deg[t]; rp[t] = deg[t]; }
        __syncthreads();
        for (int off = 1; off < 128; off <<= 1) {
            int u = 0;
            if (t < 128 && t >= off) u = rp[t - off];
            __syncthreads();
            if (t < 128) rp[t] += u;
            __syncthreads();
        }
    }
    int total = rp[127];
    for (int i = t; i < total; i += 256) csr_l[i] = n;   // sentinel only where needed
    __syncthreads();
    for (int i = t; i < cnt; i += 256) {
        int pr = binned[base + i];
        int d = pr & ((1 << BSH) - 1);
        int pos = rp[d] - dp[d] + atomicAdd(&fill[d], 1);
        csr_l[pos] = pr >> BSH;
    }
    __syncthreads();
    for (int i = t; i < total; i += 256) csr[base + i] = (ushort_t)csr_l[i];  // coalesced
    if (t < nn) {
        int start = base + rp[t] - dp[t];
        rowse[n0 + t] = make_int2(start, start + dp[t]);
        dinv[n0 + t]  = rsqrtf((float)(deg[t] + 1));   // +1 self-loop
    }
    // fused pre-scale: xn[nd][j] = dinv[nd] * x[nd][j] (fp16, coalesced float2 reads)
    for (int i = t; i < nn * 32; i += 256) {
        int r = i >> 5, l = i & 31;
        float dv = rsqrtf((float)(deg[r] + 1));
        float2 v = ((const float2*)(x + (size_t)(n0 + r) * F))[l];
        ((__half2*)(xn + (size_t)(n0 + r) * F))[l] = __floats2half2_rn(v.x * dv, v.y * dv);
    }
}

// ---------------- fused layer: fp16 gather (uint16 csr, MLP=16, csr-prefetch) -> MFMA ---
// Block = 256 thr = 4 waves = 16 nodes. MODE 1: write dinv-scaled fp16 h.
// MODE 0 (last layer): skip h write; fuse mean-pool accumulation (batch sorted).
union SMem {
    struct { short Ah[16][72]; short Al[16][72]; };   // MFMA A-tiles (hi/lo)
    struct { float vals[16][68]; int bids[16]; };     // pool staging (layer 3)
};

__device__ __forceinline__ float2 ldrow(const char* base, unsigned off) {
    return __half22float2(*(const __half2*)(base + off));   // saddr + 32b voffset form
}

template<int MODE>
__global__ __launch_bounds__(256, 8)
void k_layer(const __half* __restrict__ Hn, const int2* __restrict__ rowse,
             const ushort_t* __restrict__ csr, const float* __restrict__ dinv,
             const short* __restrict__ WhF, const short* __restrict__ WlF,
             const float* __restrict__ bias, __half* __restrict__ out,
             const int* __restrict__ batch, float* __restrict__ pooled,
             int* __restrict__ cnt, int n) {
    __shared__ SMem sm;
    __shared__ float sdinv[16];
    int t  = threadIdx.x;
    int w  = t >> 6, t6 = t & 63;
    int g  = t6 >> 5, l = t6 & 31;
    int nb0 = blockIdx.x * 16;
    const char* rowb = (const char*)Hn;
    unsigned l4 = (unsigned)l << 2;

    // ---- gather phase: 4 nodes per wave ----
    for (int q = 0; q < 4; ++q) {
        int ndl = w * 4 + q;
        int nd  = nb0 + ndl;
        float ax[8], ay[8];
        #pragma unroll
        for (int i = 0; i < 8; ++i) { ax[i] = 0.f; ay[i] = 0.f; }
        float dn = 0.f;
        if (nd < n) {
            dn = dinv[nd];
            if (g == 0) {                         // self row
                float2 f = ldrow(rowb, ((unsigned)nd << 7) + l4);
                ax[0] = f.x; ay[0] = f.y;
            }
            int2 se = rowse[nd];
            int e = se.x, e1 = se.y;
            int iters = ((e & 15) == 0) ? ((e1 - e) >> 4) : 0;
            if (iters > 0) {                      // padded (normal) path
                int4 cw = *(const int4*)(csr + e + 8 * g);
                for (int it = 0; it < iters; ++it) {
                    int4 nx = cw;                 // prefetch next csr word early
                    if (it + 1 < iters) nx = *(const int4*)(csr + e + 16 * (it + 1) + 8 * g);
                    unsigned s[8] = { (unsigned)cw.x & 0xffffu, (unsigned)cw.x >> 16,
                                      (unsigned)cw.y & 0xffffu, (unsigned)cw.y >> 16,
                                      (unsigned)cw.z & 0xffffu, (unsigned)cw.z >> 16,
                                      (unsigned)cw.w & 0xffffu, (unsigned)cw.w >> 16 };
                    #pragma unroll
                    for (int i = 0; i < 8; ++i) {
                        float2 f = ldrow(rowb, (s[i] << 7) + l4);
                        ax[i] += f.x; ay[i] += f.y;
                    }
                    cw = nx;
                }
            }
            int er = e + 16 * iters;              // remainder (ovf fallback only)
            if (g == 0) {
                for (; er < e1; ++er) {
                    float2 f = ldrow(rowb, ((unsigned)csr[er] << 7) + l4);
                    ax[7] += f.x; ay[7] += f.y;
                }
            }
        }
        float sx = ((ax[0] + ax[1]) + (ax[2] + ax[3])) + ((ax[4] + ax[5]) + (ax[6] + ax[7]));
        float sy = ((ay[0] + ay[1]) + (ay[2] + ay[3])) + ((ay[4] + ay[5]) + (ay[6] + ay[7]));
        sx += __shfl_xor(sx, 32);
        sy += __shfl_xor(sy, 32);
        sx *= dn; sy *= dn;
        if (g == 0) {
            unsigned short hx = f2bf(sx), hy = f2bf(sy);
            *(unsigned*)&sm.Ah[ndl][2 * l] = (unsigned)hx | ((unsigned)hy << 16);
            unsigned short lx = f2bf(sx - bf2f(hx)), ly = f2bf(sy - bf2f(hy));
            *(unsigned*)&sm.Al[ndl][2 * l] = (unsigned)lx | ((unsigned)ly << 16);
            if (l == 0) sdinv[ndl] = dn;
        }
    }
    __syncthreads();

    // ---- MFMA phase: wave w owns col-tile c=w ----
    int c  = w;
    int jj = t6 & 15;        // D col within tile / A row
    int kg = t6 >> 4;        // k-group
    const short8* WhP = (const short8*)WhF;
    const short8* WlP = (const short8*)WlF;
    short8 bh0 = WhP[(c * 2 + 0) * 64 + t6];
    short8 bh1 = WhP[(c * 2 + 1) * 64 + t6];
    short8 bl0 = WlP[(c * 2 + 0) * 64 + t6];
    short8 bl1 = WlP[(c * 2 + 1) * 64 + t6];
    short8 ah0 = *(const short8*)&sm.Ah[jj][kg * 8];
    short8 ah1 = *(const short8*)&sm.Ah[jj][32 + kg * 8];
    short8 al0 = *(const short8*)&sm.Al[jj][kg * 8];
    short8 al1 = *(const short8*)&sm.Al[jj][32 + kg * 8];

    float bv = bias[c * 16 + jj];
    f32x4 acc = {bv, bv, bv, bv};
    acc = __builtin_amdgcn_mfma_f32_16x16x32_bf16(ah0, bh0, acc, 0, 0, 0);
    acc = __builtin_amdgcn_mfma_f32_16x16x32_bf16(ah1, bh1, acc, 0, 0, 0);
    acc = __builtin_amdgcn_mfma_f32_16x16x32_bf16(al0, bh0, acc, 0, 0, 0);
    acc = __builtin_amdgcn_mfma_f32_16x16x32_bf16(al1, bh1, acc, 0, 0, 0);
    acc = __builtin_amdgcn_mfma_f32_16x16x32_bf16(ah0, bl0, acc, 0, 0, 0);
    acc = __builtin_amdgcn_mfma_f32_16x16x32_bf16(ah1, bl1, acc, 0, 0, 0);

    if (MODE == 1) {                 // write dinv-scaled fp16 h
        #pragma unroll
        for (int v = 0; v < 4; ++v) {
            int rr = kg * 4 + v;             // D row = local node
            int nd = nb0 + rr;
            if (nd < n) {
                float val = fmaxf(acc[v], 0.f) * sdinv[rr];
                out[(size_t)nd * F + c * 16 + jj] = __float2half(val);
            }
        }
    } else {                         // fused mean-pool accumulation (batch sorted)
        __syncthreads();             // done reading Ah/Al -> reuse LDS
        #pragma unroll
        for (int v = 0; v < 4; ++v) {
            int rr = kg * 4 + v;
            sm.vals[rr][c * 16 + jj] = fmaxf(acc[v], 0.f);
        }
        if (t < 16) sm.bids[t] = (nb0 + t < n) ? batch[nb0 + t] : -1;
        __syncthreads();
        if (t < 64) {                // per-column run-compressed atomics
            float accp = 0.f;
            int curg = sm.bids[0];
            for (int r = 0; r < 16; ++r) {
                int g2 = sm.bids[r];
                if (g2 < 0) break;
                if (g2 != curg) {
                    atomicAdd(&pooled[curg * F + t], accp);
                    curg = g2; accp = 0.f;
                }
                accp += sm.vals[r][t];
            }
            if (curg >= 0) atomicAdd(&pooled[curg * F + t], accp);
        } else if (t == 64) {        // node counts per graph
            int curg = sm.bids[0], cl = 0;
            for (int r = 0; r < 16; ++r) {
                int g2 = sm.bids[r];
                if (g2 < 0) break;
                if (g2 != curg) { atomicAdd(&cnt[curg], cl); curg = g2; cl = 0; }
                ++cl;
            }
            if (curg >= 0 && cl) atomicAdd(&cnt[curg], cl);
        }
    }
}

// ---------------- heads ----------------

__global__ void k_head(const float* __restrict__ pooled, const int* __restrict__ cnt,
                       const float* __restrict__ Wm, const float* __restrict__ bm,
                       const float* __restrict__ Wt, const float* __restrict__ bt,
                       float* __restrict__ out, int g) {
    int gid = (blockIdx.x * blockDim.x + threadIdx.x) >> 6;
    int j = threadIdx.x & 63;
    if (gid >= g) return;
    float c = fmaxf((float)cnt[gid], 1.f);
    float p = pooled[gid * F + j] / c;
    float m = p * Wm[j];
    float t = p * Wt[j];
    #pragma unroll
    for (int off = 32; off > 0; off >>= 1) {
        m += __shfl_down(m, off);
        t += __shfl_down(t, off);
    }
    if (j == 0) {
        out[gid]     = m + bm[0];
        out[g + gid] = t + bt[0];
    }
}

// ---------------- host driver ----------------

static inline size_t alignup(size_t x) { return (x + 255) & ~(size_t)255; }

extern "C" void kernel_launch(void* const* d_in, const int* in_sizes, int n_in,
                              void* d_out, int out_size, void* d_ws, size_t ws_size,
                              hipStream_t stream) {
    const float* x     = (const float*)d_in[0];
    const int*   eidx  = (const int*)d_in[1];
    const int*   batch = (const int*)d_in[2];
    const float* W1    = (const float*)d_in[3];
    const float* b1    = (const float*)d_in[4];
    const float* W2    = (const float*)d_in[5];
    const float* b2    = (const float*)d_in[6];
    const float* Wm    = (const float*)d_in[7];
    const float* bm    = (const float*)d_in[8];
    const float* Wt    = (const float*)d_in[9];
    const float* bt    = (const float*)d_in[10];
    float* out = (float*)d_out;

    const int N = in_sizes[0] / F;       // 50000
    const int E = in_sizes[1] / 2;       // 800000
    const int G = out_size / 2;          // 512
    const int* src = eidx;               // edge_index[0]
    const int* dst = eidx + E;           // edge_index[1]
    const int nbkt = (N + (1 << BSH) - 1) >> BSH;   // 391

    // workspace carve-up
    char* p = (char*)d_ws;
    float*    dinv   = (float*)p;    p += alignup(sizeof(float) * N);
    int2*     rowse  = (int2*)p;     p += alignup(sizeof(int2) * N);
    int*      bfill  = (int*)p;      p += alignup(sizeof(int) * MAXB);
    short*    Wh1    = (short*)p;    p += alignup(sizeof(short) * 4096);
    short*    Wl1    = (short*)p;    p += alignup(sizeof(short) * 4096);
    short*    Wh2    = (short*)p;    p += alignup(sizeof(short) * 4096);
    short*    Wl2    = (short*)p;    p += alignup(sizeof(short) * 4096);
    ushort_t* csr    = (ushort_t*)p; p += alignup(sizeof(ushort_t) * (size_t)nbkt * CAPB);
    int*      binned = (int*)p;      p += alignup(sizeof(int) * (size_t)nbkt * CAPB);
    __half*   xn     = (__half*)p;   p += alignup(sizeof(__half) * (size_t)(N + 1) * F);
    __half*   hA     = (__half*)p;   p += alignup(sizeof(__half) * (size_t)(N + 1) * F);
    __half*   hB     = (__half*)p;   p += alignup(sizeof(__half) * (size_t)(N + 1) * F);
    float*    pooled = (float*)p;    p += alignup(sizeof(float) * G * F);
    int*      cnt    = (int*)p;      p += alignup(sizeof(int) * G);

    const int TB = 256;

    // ---- bfill init (only dependency of binscatter) ----
    k_prep0<<<1, 512, 0, stream>>>(bfill);

    // ---- CSR build: bucketed counting sort; bincsr also runs W/sentinel/pool prep ----
    k_binscatter<<<128, TB, 0, stream>>>(src, dst, E, nbkt, bfill, binned);
    k_bincsr<<<nbkt + PREPB, TB, 0, stream>>>(binned, bfill, x, N, nbkt, csr, rowse,
                                              dinv, xn, W1, W2, Wh1, Wl1, Wh2, Wl2,
                                              hA, hB, pooled, cnt, G);

    // ---- fused layers: 16 nodes per block, fp16 gather + MFMA; layer 3 fuses pooling ----
    int gT = (N + 15) / 16;              // 3125 blocks
    k_layer<1><<<gT, TB, 0, stream>>>(xn, rowse, csr, dinv, Wh1, Wl1, b1, hA,
                                      batch, pooled, cnt, N);
    k_layer<1><<<gT, TB, 0, stream>>>(hA, rowse, csr, dinv, Wh2, Wl2, b2, hB,
                                      batch, pooled, cnt, N);
    k_layer<0><<<gT, TB, 0, stream>>>(hB, rowse, csr, dinv, Wh2, Wl2, b2, hA,
                                      batch, pooled, cnt, N);

    // ---- heads ----
    int gH = (G * F + TB - 1) / TB;
    k_head<<<gH, TB, 0, stream>>>(pooled, cnt, Wm, bm, Wt, bt, out, G);
}